// Round 7
// baseline (81.131 us; speedup 1.0000x reference)
//
#include <hip/hip_runtime.h>

// 21-qubit HEA, fp32, all-real. ONE fused kernel: R5's verified k1/k2 bodies
// (14-bit tile windows, 512 thr x 32 regs, swizzled LDS exchange) joined by a
// single device-scope grid barrier. 128 blocks x 512 thr <= 256 CUs -> all
// blocks co-resident under any scheduler packing.
//
// Barrier design (fixing R4's regression): polls are RELAXED agent-scope
// (no per-poll cache invalidate), one RELEASE fence before arrive (single
// wbl2), one ACQUIRE fence after the spin (single invalidate), tid0-only
// poll with s_sleep backoff. st traffic uses nontemporal hints so the
// release flush has ~nothing dirty. Counter zeroed per replay by memset.
//
// qubit q <-> index bit (20-q). Params: RY1 q->p[q], RY2 q->p[21+q],
// RY3 q->p[42+q]. Chain C_k = CNOT(q_k,q_{k+1}) strictly in order;
// RY2 q_k before C_{k-1},C_k; RY3 q_k after. Norm==1 by unitarity.
// Init (layer1+chain1) closed form: amp(x) = prod_b f_{20-b}(y_b),
// y_b = x_b ^ x_{b+1}, y_20 = x20 (local Gray decode; verified R3/R5).
//
// Phase 1: tile bits {20..13} u {5..0}; block owns x12..x6.
//   A(regs x4..x0):      init, RY2 q16..q20
//   B(regs x20..x16):    RY2 q0..4, C0..C3, RY3 q0..3
//   C(regs x16..x13,x5): RY2 q5,q6,q7,q15, C4..C6, RY3 q4..6
// Phase 2: tile bits {13..0}; block owns x20..x14.
//   A(regs x13..x9): RY2 q8..11, C7..C10, RY3 q7..10
//   B(regs x9..x5):  RY2 q12..14, C11..C14, RY3 q11..14
//   C(regs x5..x1):  C15..C18, RY3 q15..18
//   D(regs x4..x0):  C19, RY3 q19,q20, output

#define NQ 21
#define NSTATE (1 << NQ)
#define NBLK 128
#define BAR_OFF (32u << 20)       // byte offset of barrier counter in d_ws
#define SW(t) ((t) + ((t) >> 5))  // LDS anti-conflict: +1 word / 32 words

typedef float f32x4 __attribute__((ext_vector_type(4)));  // native vec for NT

__device__ __forceinline__ float sel(const float* cs, const float* sn, int i,
                                     int bit) {
  return bit ? sn[i] : cs[i];
}

template <int BIT, int N>
__device__ __forceinline__ void ry_bf(float (&v)[N], float c, float s) {
#pragma unroll
  for (int m = 0; m < N; ++m)
    if ((m & (1 << BIT)) == 0) {
      float a = v[m], b = v[m | (1 << BIT)];
      v[m] = c * a - s * b;
      v[m | (1 << BIT)] = s * a + c * b;
    }
}

template <int CBIT, int TBIT, int N>
__device__ __forceinline__ void cnot_rr(float (&v)[N]) {
#pragma unroll
  for (int m = 0; m < N; ++m)
    if ((m & (1 << CBIT)) && !(m & (1 << TBIT))) {
      float t = v[m];
      v[m] = v[m | (1 << TBIT)];
      v[m | (1 << TBIT)] = t;
    }
}

__device__ __forceinline__ void grid_barrier(unsigned* bar) {
  __syncthreads();
  if (threadIdx.x == 0) {
    __builtin_amdgcn_fence(__ATOMIC_RELEASE, "agent");  // one wbl2
    __hip_atomic_fetch_add(bar, 1u, __ATOMIC_RELAXED,
                           __HIP_MEMORY_SCOPE_AGENT);
    unsigned cnt;
    do {
      __builtin_amdgcn_s_sleep(8);
      cnt = __hip_atomic_load(bar, __ATOMIC_RELAXED,
                              __HIP_MEMORY_SCOPE_AGENT);  // no inv per poll
    } while (cnt < NBLK);
    __builtin_amdgcn_fence(__ATOMIC_ACQUIRE, "agent");  // one invalidate
  }
  __syncthreads();
}

__global__ __launch_bounds__(512) void fused(const float* __restrict__ p,
                                             float* __restrict__ st,
                                             float* __restrict__ out,
                                             int outmode,
                                             unsigned* __restrict__ bar) {
  __shared__ float cs[63], sn[63];
  __shared__ float ex[16896];   // 16384 + swizzle pad
  const int tid = threadIdx.x;  // 9 bits
  const int bid = blockIdx.x;   // 7 bits
  if (tid < 63) {
    float h = 0.5f * p[tid];
    cs[tid] = cosf(h);
    sn[tid] = sinf(h);
  }
  __syncthreads();

  float v[32];

  // ================ Phase 1: block owns x12..x6 = bid ================
  {
    // ---- Layout A: regs r_j = x_j (j=0..4); tid0=x5; (tid>>1)_k = x_{13+k}
    const int h = tid >> 1;           // h_k = x_{13+k}
    const int e5 = tid & 1;           // x5
    const int gb = bid ^ (bid >> 1);  // y_{6+i} = gb_i (i=0..5)
    const int u = h ^ (h >> 1);       // y_{13+k} = u_k (k=0..6)

    float Pre = sel(cs, sn, 15, e5 ^ (bid & 1));  // y5, p15
    Pre *= sel(cs, sn, 8, ((bid >> 6) ^ h) & 1);  // y12, p8
    Pre *= sel(cs, sn, 0, (h >> 7) & 1);          // y20, p0
#pragma unroll
    for (int i = 0; i < 6; ++i) Pre *= sel(cs, sn, 14 - i, (gb >> i) & 1);
#pragma unroll
    for (int k = 0; k < 7; ++k) Pre *= sel(cs, sn, 7 - k, (u >> k) & 1);

#pragma unroll
    for (int r = 0; r < 32; ++r) {
      const int gr = r ^ (r >> 1);  // y_j = gr_j (j=0..3); y4 = gr_4 ^ x5
      float prod = Pre;
      prod *= sel(cs, sn, 20, gr & 1);
      prod *= sel(cs, sn, 19, (gr >> 1) & 1);
      prod *= sel(cs, sn, 18, (gr >> 2) & 1);
      prod *= sel(cs, sn, 17, (gr >> 3) & 1);
      prod *= sel(cs, sn, 16, ((gr >> 4) ^ e5) & 1);
      v[r] = prod;
    }
    // RY2 q16..q20 -> bits 4..0, params 37..41
    ry_bf<4>(v, cs[37], sn[37]);
    ry_bf<3>(v, cs[38], sn[38]);
    ry_bf<2>(v, cs[39], sn[39]);
    ry_bf<1>(v, cs[40], sn[40]);
    ry_bf<0>(v, cs[41], sn[41]);

    // Exchange A -> B. Canonical t[13:6]=x20..13, t[5:0]=x5..0.
#pragma unroll
    for (int r = 0; r < 32; ++r) ex[SW((tid << 5) | r)] = v[r];
    __syncthreads();
    // ---- Layout B: regs r_j = x_{16+j}; tid[8:6]=x15..x13, tid[5:0]=x5..x0
#pragma unroll
    for (int r = 0; r < 32; ++r) v[r] = ex[SW((r << 9) | tid)];
    __syncthreads();

    // RY2 q0..q4 (p21..25 -> r4..r0), C0..C3, RY3 q0..3 (p42..45)
    ry_bf<4>(v, cs[21], sn[21]);
    ry_bf<3>(v, cs[22], sn[22]);
    ry_bf<2>(v, cs[23], sn[23]);
    ry_bf<1>(v, cs[24], sn[24]);
    ry_bf<0>(v, cs[25], sn[25]);
    cnot_rr<4, 3>(v);
    cnot_rr<3, 2>(v);
    cnot_rr<2, 1>(v);
    cnot_rr<1, 0>(v);
    ry_bf<4>(v, cs[42], sn[42]);
    ry_bf<3>(v, cs[43], sn[43]);
    ry_bf<2>(v, cs[44], sn[44]);
    ry_bf<1>(v, cs[45], sn[45]);

    // Exchange B -> C.
#pragma unroll
    for (int r = 0; r < 32; ++r) ex[SW((r << 9) | tid)] = v[r];
    __syncthreads();
    // ---- Layout C: r4..r1 = x16..x13, r0 = x5; tid[8:5]=x20..x17,
    //      tid[4:0]=x4..x0
#pragma unroll
    for (int r = 0; r < 32; ++r)
      v[r] = ex[SW(((tid >> 5) << 10) | ((r >> 1) << 6) | ((r & 1) << 5) |
                   (tid & 31))];

    // RY2 q5(p26,r3), q6(p27,r2), q7(p28,r1), q15(p36,r0);
    // C4 <4,3>, C5 <3,2>, C6 <2,1>; RY3 q4(p46,r4), q5(p47,r3), q6(p48,r2)
    ry_bf<3>(v, cs[26], sn[26]);
    ry_bf<2>(v, cs[27], sn[27]);
    ry_bf<1>(v, cs[28], sn[28]);
    ry_bf<0>(v, cs[36], sn[36]);
    cnot_rr<4, 3>(v);
    cnot_rr<3, 2>(v);
    cnot_rr<2, 1>(v);
    ry_bf<4>(v, cs[46], sn[46]);
    ry_bf<3>(v, cs[47], sn[47]);
    ry_bf<2>(v, cs[48], sn[48]);

    // Store (nontemporal): x = x20..x17 | x16..x13 | bid | x5 | x4..x0
#pragma unroll
    for (int r = 0; r < 32; ++r)
      __builtin_nontemporal_store(
          v[r], &st[((tid >> 5) << 17) | ((r >> 1) << 13) | (bid << 6) |
                    ((r & 1) << 5) | (tid & 31)]);
  }

  grid_barrier(bar);

  // ================ Phase 2: block owns x20..x14 = bid ================
  {
    const int xb = bid << 14;

    // ---- Layout A: regs r_j = x_{9+j}; tid = x8..x0
#pragma unroll
    for (int r = 0; r < 32; ++r)
      v[r] = __builtin_nontemporal_load(&st[xb | (r << 9) | tid]);

    // RY2 q8(p29,r3), q9(p30,r2), q10(p31,r1), q11(p32,r0);
    // C7 <4,3>, C8 <3,2>, C9 <2,1>, C10 <1,0>;
    // RY3 q7(p49,r4), q8(p50,r3), q9(p51,r2), q10(p52,r1)
    ry_bf<3>(v, cs[29], sn[29]);
    ry_bf<2>(v, cs[30], sn[30]);
    ry_bf<1>(v, cs[31], sn[31]);
    ry_bf<0>(v, cs[32], sn[32]);
    cnot_rr<4, 3>(v);
    cnot_rr<3, 2>(v);
    cnot_rr<2, 1>(v);
    cnot_rr<1, 0>(v);
    ry_bf<4>(v, cs[49], sn[49]);
    ry_bf<3>(v, cs[50], sn[50]);
    ry_bf<2>(v, cs[51], sn[51]);
    ry_bf<1>(v, cs[52], sn[52]);

    // Exchange A -> B. Canonical t = x13..x0.
#pragma unroll
    for (int r = 0; r < 32; ++r) ex[SW((r << 9) | tid)] = v[r];
    __syncthreads();
    // ---- Layout B: regs r_j = x_{5+j}; tid[8:5]=x13..x10, tid[4:0]=x4..x0
#pragma unroll
    for (int r = 0; r < 32; ++r)
      v[r] = ex[SW(((tid >> 5) << 10) | (r << 5) | (tid & 31))];
    __syncthreads();

    // RY2 q12(p33,r3), q13(p34,r2), q14(p35,r1);
    // C11 <4,3>, C12 <3,2>, C13 <2,1>, C14 <1,0>;
    // RY3 q11(p53,r4), q12(p54,r3), q13(p55,r2), q14(p56,r1)
    ry_bf<3>(v, cs[33], sn[33]);
    ry_bf<2>(v, cs[34], sn[34]);
    ry_bf<1>(v, cs[35], sn[35]);
    cnot_rr<4, 3>(v);
    cnot_rr<3, 2>(v);
    cnot_rr<2, 1>(v);
    cnot_rr<1, 0>(v);
    ry_bf<4>(v, cs[53], sn[53]);
    ry_bf<3>(v, cs[54], sn[54]);
    ry_bf<2>(v, cs[55], sn[55]);
    ry_bf<1>(v, cs[56], sn[56]);

    // Exchange B -> C.
#pragma unroll
    for (int r = 0; r < 32; ++r)
      ex[SW(((tid >> 5) << 10) | (r << 5) | (tid & 31))] = v[r];
    __syncthreads();
    // ---- Layout C: regs r_j = x_{1+j}; tid[8:1]=x13..x6, tid[0]=x0
#pragma unroll
    for (int r = 0; r < 32; ++r)
      v[r] = ex[SW(((tid >> 1) << 6) | (r << 1) | (tid & 1))];
    __syncthreads();

    // C15 <4,3>, C16 <3,2>, C17 <2,1>, C18 <1,0>;
    // RY3 q15(p57,r4), q16(p58,r3), q17(p59,r2), q18(p60,r1)
    cnot_rr<4, 3>(v);
    cnot_rr<3, 2>(v);
    cnot_rr<2, 1>(v);
    cnot_rr<1, 0>(v);
    ry_bf<4>(v, cs[57], sn[57]);
    ry_bf<3>(v, cs[58], sn[58]);
    ry_bf<2>(v, cs[59], sn[59]);
    ry_bf<1>(v, cs[60], sn[60]);

    // Exchange C -> D.
#pragma unroll
    for (int r = 0; r < 32; ++r)
      ex[SW(((tid >> 1) << 6) | (r << 1) | (tid & 1))] = v[r];
    __syncthreads();
    // ---- Layout D: regs r_j = x_j; tid = x13..x5
#pragma unroll
    for (int r = 0; r < 32; ++r) v[r] = ex[SW((tid << 5) | r)];

    // C19 <1,0>; RY3 q19(p61,bit1), q20(p62,bit0)
    cnot_rr<1, 0>(v);
    ry_bf<1>(v, cs[61], sn[61]);
    ry_bf<0>(v, cs[62], sn[62]);

    // Output: thread owns 32 consecutive elements (nontemporal 16B stores).
    const int base = xb | (tid << 5);
    if (outmode == 2) {
      f32x4* o4 = (f32x4*)out;  // interleaved complex (re, 0)
#pragma unroll
      for (int i = 0; i < 16; ++i) {
        f32x4 w = {v[2 * i], 0.0f, v[2 * i + 1], 0.0f};
        __builtin_nontemporal_store(w, &o4[(base >> 1) + i]);
      }
    } else {
      f32x4* o4 = (f32x4*)(out + base);
#pragma unroll
      for (int j = 0; j < 8; ++j) {
        f32x4 w = {v[4 * j], v[4 * j + 1], v[4 * j + 2], v[4 * j + 3]};
        __builtin_nontemporal_store(w, &o4[j]);
      }
    }
  }
}

extern "C" void kernel_launch(void* const* d_in, const int* in_sizes, int n_in,
                              void* d_out, int out_size, void* d_ws,
                              size_t ws_size, hipStream_t stream) {
  const float* p = (const float*)d_in[0];  // 63 fp32 params
  float* out = (float*)d_out;
  float* st = (float*)d_ws;  // 2^21 floats = 8 MB scratch
  unsigned* bar = (unsigned*)((char*)d_ws + BAR_OFF);
  const int outmode = (out_size == 2 * NSTATE) ? 2 : 1;

  // Zero the barrier counter each call (graph node, re-runs every replay).
  (void)hipMemsetAsync((void*)bar, 0, sizeof(unsigned), stream);
  fused<<<NBLK, 512, 0, stream>>>(p, st, out, outmode, bar);
}

// Round 9
// 68.622 us; speedup vs baseline: 1.1823x; 1.1823x over previous
//
#include <hip/hip_runtime.h>

// 21-qubit HEA, fp32, all-real. ONE kernel, NO grid barrier, NO global state
// round-trip. Factorization: U_total = U2 * U1 * |init>, where
//   U1 = {RY2 q0..q7, C0..C6, RY3 q0..q6}    acts only on bits 20..13,
//   U2 = {RY2 q8..q20, C7..C19, RY3 q7..q20} acts only on bits 13..0.
// (Proved: RY2 q8..20 commute right past RY3 q0..6 and C0..C6; RY3 q0..6
//  commute left past C7..C19 — all disjoint-qubit moves.)
// init (layer1+chain1): amp(x) = F(z) * sel(p8, L12^z0) * G(L),
// z = x20..x13 (z_j = x_{13+j}), L = x12..x0, local-Gray y_b = x_b^x_{b+1}.
// Block fixes H = bid = x20..x14. From U1 only a(x13,c) = (U1 Phi_c)(z*),
// z* = (bid<<1)|x13, Phi_c(z) = F(z)[z0==c]: a 512-dim (c,z) sim done
// redundantly per wave in regs: lane = (c<<5)|(z>>3), regs e = z2..z0;
// z-bits 3..7 via __shfl_xor butterflies, z-bits 0..2 in-reg.
// Then W[x13][x12] = a(x13,0)*sel(p8,x12) + a(x13,1)*sel(p8,~x12),
// v[r] = G(L) * W and U2 runs as R5-k2's verified layouts A-D.
// GATE LEDGER (R8 bug: p36..41 were dropped): RY2 q15(p36)->layout B;
// q16..q19(p37..40)->layout C top; q20(p41)->layout D. Each precedes the
// first CNOT touching its qubit (C14/C15../C19); legal by commutation.
// qubit q <-> bit 20-q; params RY1 q->p[q], RY2 q->p[21+q], RY3 q->p[42+q].
// Norm == 1 by unitarity.

#define NQ 21
#define NSTATE (1 << NQ)
#define SW(t) ((t) + ((t) >> 5))  // LDS anti-conflict: +1 word / 32 words

typedef float f32x4 __attribute__((ext_vector_type(4)));

__device__ __forceinline__ float sel(const float* cs, const float* sn, int i,
                                     int bit) {
  return bit ? sn[i] : cs[i];
}

template <int BIT, int N>
__device__ __forceinline__ void ry_bf(float (&v)[N], float c, float s) {
#pragma unroll
  for (int m = 0; m < N; ++m)
    if ((m & (1 << BIT)) == 0) {
      float a = v[m], b = v[m | (1 << BIT)];
      v[m] = c * a - s * b;
      v[m | (1 << BIT)] = s * a + c * b;
    }
}

template <int CBIT, int TBIT, int N>
__device__ __forceinline__ void cnot_rr(float (&v)[N]) {
#pragma unroll
  for (int m = 0; m < N; ++m)
    if ((m & (1 << CBIT)) && !(m & (1 << TBIT))) {
      float t = v[m];
      v[m] = v[m | (1 << TBIT)];
      v[m | (1 << TBIT)] = t;
    }
}

// CNOT with control outside the register index (cond), target reg bit.
template <int TBIT, int N>
__device__ __forceinline__ void cswap_bf(float (&v)[N], bool cond) {
#pragma unroll
  for (int m = 0; m < N; ++m)
    if ((m & (1 << TBIT)) == 0) {
      float a = v[m], b = v[m | (1 << TBIT)];
      v[m] = cond ? b : a;
      v[m | (1 << TBIT)] = cond ? a : b;
    }
}

// RY on a z-bit living in the LANE index (shfl butterfly).
template <int MASK>
__device__ __forceinline__ void ry_shfl(float (&u)[8], float c, float s,
                                        int lane) {
  const float ss = (lane & MASK) ? s : -s;
#pragma unroll
  for (int e = 0; e < 8; ++e) {
    float w = __shfl_xor(u[e], MASK);
    u[e] = c * u[e] + ss * w;
  }
}

// CNOT: ctrl lane-bit mask CMASK, tgt lane-bit mask TMASK.
template <int CMASK, int TMASK>
__device__ __forceinline__ void cnot_shfl(float (&u)[8], int lane) {
  const bool ctrl = (lane & CMASK) != 0;
#pragma unroll
  for (int e = 0; e < 8; ++e) {
    float w = __shfl_xor(u[e], TMASK);
    u[e] = ctrl ? w : u[e];
  }
}

__global__ __launch_bounds__(512) void fused(const float* __restrict__ p,
                                             float* __restrict__ out,
                                             int outmode) {
  __shared__ float cs[63], sn[63];
  __shared__ float ex[16896];   // 16384 + swizzle pad
  const int tid = threadIdx.x;  // 9 bits
  const int bid = blockIdx.x;   // 7 bits: bid_i = x_{14+i}
  if (tid < 63) {
    float h = 0.5f * p[tid];
    cs[tid] = cosf(h);
    sn[tid] = sinf(h);
  }
  __syncthreads();

  // ========== U1 pre-sim: 512-dim (c,z), redundant per wave ==========
  const int lane = tid & 63;  // lane = (c<<5) | (z>>3); regs e = z2..z0
  float u[8];
  {
    const int zh = (lane & 31) << 3;
    const int c = lane >> 5;
#pragma unroll
    for (int e = 0; e < 8; ++e) {
      const int z = zh | e;
      const int gz = z ^ (z >> 1);  // bit j = z_j ^ z_{j+1} (j<7)
      float F = sel(cs, sn, 0, (z >> 7) & 1);
#pragma unroll
      for (int j = 0; j < 7; ++j) F *= sel(cs, sn, 7 - j, (gz >> j) & 1);
      u[e] = ((z & 1) == c) ? F : 0.0f;
    }
  }
  // RY2 q0..q7 (p21..p28) on z7..z0  (qubit k = z_{7-k})
  ry_shfl<16>(u, cs[21], sn[21], lane);
  ry_shfl<8>(u, cs[22], sn[22], lane);
  ry_shfl<4>(u, cs[23], sn[23], lane);
  ry_shfl<2>(u, cs[24], sn[24], lane);
  ry_shfl<1>(u, cs[25], sn[25], lane);
  ry_bf<2>(u, cs[26], sn[26]);
  ry_bf<1>(u, cs[27], sn[27]);
  ry_bf<0>(u, cs[28], sn[28]);
  // C0..C6 down the chain
  cnot_shfl<16, 8>(u, lane);        // C0: ctrl z7, tgt z6
  cnot_shfl<8, 4>(u, lane);         // C1
  cnot_shfl<4, 2>(u, lane);         // C2
  cnot_shfl<2, 1>(u, lane);         // C3
  cswap_bf<2>(u, (lane & 1) != 0);  // C4: ctrl z3 (lane0), tgt z2 (reg2)
  cnot_rr<2, 1>(u);                 // C5
  cnot_rr<1, 0>(u);                 // C6
  // RY3 q0..q6 (p42..p48) on z7..z1
  ry_shfl<16>(u, cs[42], sn[42], lane);
  ry_shfl<8>(u, cs[43], sn[43], lane);
  ry_shfl<4>(u, cs[44], sn[44], lane);
  ry_shfl<2>(u, cs[45], sn[45], lane);
  ry_shfl<1>(u, cs[46], sn[46], lane);
  ry_bf<2>(u, cs[47], sn[47]);
  ry_bf<1>(u, cs[48], sn[48]);

  // Extract a(x13,c): z* = (bid<<1)|x13 -> lane* = (c<<5)|(bid>>2),
  // reg e* = ((bid&3)<<1)|x13 (bid-uniform select + shfl broadcast).
  const int b3 = bid & 3;
  const float ue0 = b3 == 0 ? u[0] : b3 == 1 ? u[2] : b3 == 2 ? u[4] : u[6];
  const float ue1 = b3 == 0 ? u[1] : b3 == 1 ? u[3] : b3 == 2 ? u[5] : u[7];
  const int l0 = bid >> 2;
  const float a00 = __shfl(ue0, l0);       // x13=0, c=0
  const float a01 = __shfl(ue0, 32 | l0);  // x13=0, c=1
  const float a10 = __shfl(ue1, l0);       // x13=1, c=0
  const float a11 = __shfl(ue1, 32 | l0);  // x13=1, c=1
  float W[2][2];
  W[0][0] = a00 * cs[8] + a01 * sn[8];
  W[0][1] = a00 * sn[8] + a01 * cs[8];
  W[1][0] = a10 * cs[8] + a11 * sn[8];
  W[1][1] = a10 * sn[8] + a11 * cs[8];

  // ========== Phase 2 (U2 on bits 13..0), R5-k2 verified body ==========
  float v[32];
  // ---- Layout A: regs r_j = x_{9+j} (r4=x13..r0=x9); tid = x8..x0.
  {
    const int gt = tid ^ (tid >> 1);  // bit b = tid_b ^ tid_{b+1}, b<8
    float tcommon = 1.0f;
#pragma unroll
    for (int b = 0; b < 8; ++b)
      tcommon *= sel(cs, sn, 20 - b, (gt >> b) & 1);
    const int t8 = (tid >> 8) & 1;  // x8
#pragma unroll
    for (int r = 0; r < 32; ++r) {
      const int gr = r ^ (r >> 1);  // gr_0=y9, gr_1=y10, gr_2=y11
      float prod = tcommon * W[(r >> 4) & 1][(r >> 3) & 1];
      prod *= sel(cs, sn, 12, t8 ^ (r & 1));  // y8 = x8 ^ x9
      prod *= sel(cs, sn, 11, gr & 1);
      prod *= sel(cs, sn, 10, (gr >> 1) & 1);
      prod *= sel(cs, sn, 9, (gr >> 2) & 1);
      v[r] = prod;
    }
  }

  // RY2 q8..q11 (p29..32, r3..r0); C7..C10; RY3 q7..q10 (p49..52, r4..r1)
  ry_bf<3>(v, cs[29], sn[29]);
  ry_bf<2>(v, cs[30], sn[30]);
  ry_bf<1>(v, cs[31], sn[31]);
  ry_bf<0>(v, cs[32], sn[32]);
  cnot_rr<4, 3>(v);
  cnot_rr<3, 2>(v);
  cnot_rr<2, 1>(v);
  cnot_rr<1, 0>(v);
  ry_bf<4>(v, cs[49], sn[49]);
  ry_bf<3>(v, cs[50], sn[50]);
  ry_bf<2>(v, cs[51], sn[51]);
  ry_bf<1>(v, cs[52], sn[52]);

  // Exchange A -> B. Canonical t = x13..x0.
#pragma unroll
  for (int r = 0; r < 32; ++r) ex[SW((r << 9) | tid)] = v[r];
  __syncthreads();
  // ---- Layout B: regs r_j = x_{5+j}; tid[8:5]=x13..x10, tid[4:0]=x4..x0
#pragma unroll
  for (int r = 0; r < 32; ++r)
    v[r] = ex[SW(((tid >> 5) << 10) | (r << 5) | (tid & 31))];
  __syncthreads();

  // RY2 q12..q14 (p33..35, r3..r1) + q15 (p36, r0=x5, before C14);
  // C11..C14; RY3 q11..q14 (p53..56, r4..r1)
  ry_bf<3>(v, cs[33], sn[33]);
  ry_bf<2>(v, cs[34], sn[34]);
  ry_bf<1>(v, cs[35], sn[35]);
  ry_bf<0>(v, cs[36], sn[36]);
  cnot_rr<4, 3>(v);
  cnot_rr<3, 2>(v);
  cnot_rr<2, 1>(v);
  cnot_rr<1, 0>(v);
  ry_bf<4>(v, cs[53], sn[53]);
  ry_bf<3>(v, cs[54], sn[54]);
  ry_bf<2>(v, cs[55], sn[55]);
  ry_bf<1>(v, cs[56], sn[56]);

  // Exchange B -> C.
#pragma unroll
  for (int r = 0; r < 32; ++r)
    ex[SW(((tid >> 5) << 10) | (r << 5) | (tid & 31))] = v[r];
  __syncthreads();
  // ---- Layout C: regs r_j = x_{1+j} (r4=x5..r0=x1); tid[8:1]=x13..x6,
  //      tid[0]=x0
#pragma unroll
  for (int r = 0; r < 32; ++r)
    v[r] = ex[SW(((tid >> 1) << 6) | (r << 1) | (tid & 1))];
  __syncthreads();

  // RY2 q16..q19 (p37..40 on bits 4..1 = r3..r0, before C15);
  // C15..C18; RY3 q15..q18 (p57..60, r4..r1)
  ry_bf<3>(v, cs[37], sn[37]);
  ry_bf<2>(v, cs[38], sn[38]);
  ry_bf<1>(v, cs[39], sn[39]);
  ry_bf<0>(v, cs[40], sn[40]);
  cnot_rr<4, 3>(v);
  cnot_rr<3, 2>(v);
  cnot_rr<2, 1>(v);
  cnot_rr<1, 0>(v);
  ry_bf<4>(v, cs[57], sn[57]);
  ry_bf<3>(v, cs[58], sn[58]);
  ry_bf<2>(v, cs[59], sn[59]);
  ry_bf<1>(v, cs[60], sn[60]);

  // Exchange C -> D.
#pragma unroll
  for (int r = 0; r < 32; ++r)
    ex[SW(((tid >> 1) << 6) | (r << 1) | (tid & 1))] = v[r];
  __syncthreads();
  // ---- Layout D: regs r_j = x_j; tid = x13..x5
#pragma unroll
  for (int r = 0; r < 32; ++r) v[r] = ex[SW((tid << 5) | r)];

  // RY2 q20 (p41, bit0=r0, before C19); C19 <1,0>;
  // RY3 q19 (p61, bit1), q20 (p62, bit0)
  ry_bf<0>(v, cs[41], sn[41]);
  cnot_rr<1, 0>(v);
  ry_bf<1>(v, cs[61], sn[61]);
  ry_bf<0>(v, cs[62], sn[62]);

  // Output: thread owns 32 consecutive elements (nontemporal 16B stores).
  const int base = (bid << 14) | (tid << 5);
  if (outmode == 2) {
    f32x4* o4 = (f32x4*)out;  // interleaved complex (re, 0)
#pragma unroll
    for (int i = 0; i < 16; ++i) {
      f32x4 w = {v[2 * i], 0.0f, v[2 * i + 1], 0.0f};
      __builtin_nontemporal_store(w, &o4[(base >> 1) + i]);
    }
  } else {
    f32x4* o4 = (f32x4*)(out + base);
#pragma unroll
    for (int j = 0; j < 8; ++j) {
      f32x4 w = {v[4 * j], v[4 * j + 1], v[4 * j + 2], v[4 * j + 3]};
      __builtin_nontemporal_store(w, &o4[j]);
    }
  }
}

extern "C" void kernel_launch(void* const* d_in, const int* in_sizes, int n_in,
                              void* d_out, int out_size, void* d_ws,
                              size_t ws_size, hipStream_t stream) {
  const float* p = (const float*)d_in[0];  // 63 fp32 params
  float* out = (float*)d_out;
  const int outmode = (out_size == 2 * NSTATE) ? 2 : 1;
  fused<<<128, 512, 0, stream>>>(p, out, outmode);
}